// Round 11
// baseline (482.761 us; speedup 1.0000x reference)
//
#include <hip/hip_runtime.h>

// TwoLayerSNN forward: B=256, T=1000, D=32, H=200, O=2
// Round 11 = round 10 (passing, 197us) with the LDS x-path deleted:
// producers read x via wave-uniform scalar loads (s_load through k$/L2,
// operand folded into v_pk_fma as the single SGPR source). Removes 256
// redundant ds_read_b128 per sub-chunk from the shared LDS pipe and the
// whole xls staging state machine. Dot arithmetic keeps the exact pk
// pairing -> bit-identical to r9/r10. Consumers / wave-8 layer-2 / partv /
// barrier structure textually r10's.

constexpr int TB = 256;
constexpr int TT = 1000;
constexpr int DD = 32;
constexpr int HH = 200;
constexpr int OO = 2;
constexpr int SC = 8;                     // timesteps per barrier interval
constexpr int NSC = TT / SC;              // 125

typedef float v2f __attribute__((ext_vector_type(2)));

__device__ __forceinline__ v2f pk_fma(v2f a, v2f b, v2f c) {
#if __has_builtin(__builtin_elementwise_fma)
    return __builtin_elementwise_fma(a, b, c);
#else
    v2f r; r.x = fmaf(a.x, b.x, c.x); r.y = fmaf(a.y, b.y, c.y); return r;
#endif
}

__device__ __forceinline__ void wave_sum2(float& a, float& b) {
    // wave64 sum; result valid in lane 63 of each wave. (verified r2/6-r10)
#define DPP_STEP(CTRL)                                                          \
    {                                                                           \
        int ta = __builtin_amdgcn_update_dpp(0, __float_as_int(a), CTRL, 0xf, 0xf, true); \
        int tb = __builtin_amdgcn_update_dpp(0, __float_as_int(b), CTRL, 0xf, 0xf, true); \
        a += __int_as_float(ta);                                                \
        b += __int_as_float(tb);                                                \
    }
    DPP_STEP(0x111)  // row_shr:1
    DPP_STEP(0x112)  // row_shr:2
    DPP_STEP(0x114)  // row_shr:4
    DPP_STEP(0x118)  // row_shr:8
    DPP_STEP(0x142)  // row_bcast:15
    DPP_STEP(0x143)  // row_bcast:31
#undef DPP_STEP
}

__device__ __forceinline__ void block_sync_lds() {
    // Order LDS only (validated r8-r10): drain lgkm, raw barrier.
    asm volatile("s_waitcnt lgkmcnt(0)" ::: "memory");
    __builtin_amdgcn_s_barrier();
    asm volatile("" ::: "memory");
}

__global__ __launch_bounds__(576, 1)
void snn_fwd(const float* __restrict__ x,
             const float* __restrict__ w1,
             const float* __restrict__ w2,
             float* __restrict__ out)
{
    const int b    = blockIdx.x;
    const int tid  = threadIdx.x;
    const int lane = tid & 63;
    const int wid  = tid >> 6;
    const bool is_cons = (wid < 4);             // waves 0-3: consumers
    const bool is_prod = (wid >= 4 && wid < 8); // waves 4-7: producers
    const bool act = is_cons && (tid < HH);

    float* __restrict__ outp = out;                        // [TB][OO]
    float* __restrict__ s1o  = out + (size_t)TB * OO;      // [TB][TT][HH]
    float* __restrict__ m1o  = s1o + (size_t)TB * TT * HH; // [TB][TT][HH]
    float* __restrict__ s2o  = m1o + (size_t)TB * TT * HH; // [TB][TT][OO]
    float* __restrict__ m2o  = s2o + (size_t)TB * TT * OO; // [TB][TT][OO]

    const float A_SYN1 = (float)0.8187307530779818;
    const float IN_SC1 = (float)((1.0 - 0.8187307530779818) * 5.0);
    const float A_MEM1 = (float)0.9048374180359595;
    const float B_MEM1 = (float)(1.0 - 0.9048374180359595);
    const float TH1    = 0.5f;
    const float A_SYN2 = (float)0.9048374180359595;
    const float IN_SC2 = (float)((1.0 - 0.9048374180359595) * 10.0);
    const float A_MEM2 = (float)0.9512294245007140;
    const float B_MEM2 = (float)(1.0 - 0.9512294245007140);
    const float TH2    = 1.0f;

    __shared__ float  dotb[2][SC][HH];               // dot dbuf, 6.4 KB ea
    __shared__ __align__(16) float2 partv[2][SC][4]; // parity x step x wave

    const float* __restrict__ xb = x + (size_t)b * TT * DD;

    // producer: 50 hidden units per wave; w1 column as 16 float2 pairs
    const int ph   = (wid - 4) * 50 + lane;          // producer h
    const bool pact = is_prod && (lane < 50);
    v2f w1e[DD / 4], w1o[DD / 4];
#pragma unroll
    for (int i = 0; i < DD / 4; ++i) {
        w1e[i] = pact ? v2f{w1[(4 * i) * HH + ph],     w1[(4 * i + 1) * HH + ph]} : v2f{0.f, 0.f};
        w1o[i] = pact ? v2f{w1[(4 * i + 2) * HH + ph], w1[(4 * i + 3) * HH + ph]} : v2f{0.f, 0.f};
    }
    // consumer: w2 row
    const float w2x = act ? w2[tid * OO + 0] : 0.0f;
    const float w2y = act ? w2[tid * OO + 1] : 0.0f;

    // produce(j): dots for sub-chunk j into dotb[j&1].
    // x read via wave-uniform scalar loads (s_load); pk pairing bit-identical.
    auto produce = [&](int j) {
        const int tj = j * SC;
#pragma unroll
        for (int s = 0; s < SC; ++s) {
            const float* __restrict__ xr = xb + (size_t)(tj + s) * DD;
            float xv[DD];
#pragma unroll
            for (int d = 0; d < DD; ++d) xv[d] = xr[d];
            v2f A01 = {0.f, 0.f}, A23 = {0.f, 0.f};
#pragma unroll
            for (int i = 0; i < DD / 4; ++i) {
                A01 = pk_fma(v2f{xv[4 * i],     xv[4 * i + 1]}, w1e[i], A01);
                A23 = pk_fma(v2f{xv[4 * i + 2], xv[4 * i + 3]}, w1o[i], A23);
            }
            const float dotv = __fadd_rn(__fadd_rn(A01.x, A01.y),
                                         __fadd_rn(A23.x, A23.y));
            if (pact) dotb[j & 1][s][ph] = dotv;
        }
    };

    // prologue: fill dotb[0] for sub-chunk 0
    if (is_prod) produce(0);
    block_sync_lds();

    float syn1 = 0.0f, mem1 = 0.0f;
    float syn2x = 0.0f, syn2y = 0.0f, mem2x = 0.0f, mem2y = 0.0f;
    double accx = 0.0, accy = 0.0;

    float* __restrict__ s1p = s1o + (size_t)b * TT * HH + tid;
    float* __restrict__ m1p = m1o + (size_t)b * TT * HH + tid;
    float2* __restrict__ s2p = (float2*)(s2o + (size_t)b * TT * OO);
    float2* __restrict__ m2p = (float2*)(m2o + (size_t)b * TT * OO);

    // layer-2 for sub-chunk j (wave 8 only; burst-reads partv[j&1] from LDS)
    auto l2_chunk = [&](int j) {
        float4 P[16];
        const float4* pvall = (const float4*)&partv[j & 1][0][0];
#pragma unroll
        for (int i = 0; i < 16; ++i) P[i] = pvall[i];
#pragma unroll
        for (int s = 0; s < SC; ++s) {
            const float4 q0 = P[2 * s];
            const float4 q1 = P[2 * s + 1];
            const float dx = __fadd_rn(__fadd_rn(q0.x, q0.z), __fadd_rn(q1.x, q1.z));
            const float dy = __fadd_rn(__fadd_rn(q0.y, q0.w), __fadd_rn(q1.y, q1.w));
            syn2x = __fadd_rn(__fmul_rn(A_SYN2, syn2x), __fmul_rn(IN_SC2, dx));
            syn2y = __fadd_rn(__fmul_rn(A_SYN2, syn2y), __fmul_rn(IN_SC2, dy));
            mem2x = __fadd_rn(__fmul_rn(A_MEM2, mem2x), __fmul_rn(B_MEM2, syn2x));
            mem2y = __fadd_rn(__fmul_rn(A_MEM2, mem2y), __fmul_rn(B_MEM2, syn2y));
            const float s2x = (mem2x - TH2 > 0.0f) ? 1.0f : 0.0f;
            const float s2y = (mem2y - TH2 > 0.0f) ? 1.0f : 0.0f;
            mem2x = __fsub_rn(mem2x, __fmul_rn(s2x, TH2));
            mem2y = __fsub_rn(mem2y, __fmul_rn(s2y, TH2));
            const int t = j * SC + s;
            if (tid == 512) {
                s2p[t] = make_float2(s2x, s2y);
                m2p[t] = make_float2(mem2x, mem2y);
            }
            if (t > 0) { accx += (double)mem2x; accy += (double)mem2y; }
        }
    };

    for (int sc = 0; sc < NSC; ++sc) {
        const int t0 = sc * SC;

        if (is_cons) {
            // ---- consumer: this sub-chunk's dots from LDS ----
            float D[SC];
#pragma unroll
            for (int s = 0; s < SC; ++s) D[s] = dotb[sc & 1][s][tid];

            // ---- 8 steps: recurrence + stores + DPP (textually r10's) ----
#pragma unroll
            for (int s = 0; s < SC; ++s) {
                const float dot = D[s];
                syn1 = __fadd_rn(__fmul_rn(A_SYN1, syn1), __fmul_rn(IN_SC1, dot));
                mem1 = __fadd_rn(__fmul_rn(A_MEM1, mem1), __fmul_rn(B_MEM1, syn1));
                const float s1v = (mem1 - TH1 > 0.0f) ? 1.0f : 0.0f;
                mem1 = __fsub_rn(mem1, __fmul_rn(s1v, TH1));

                if (act) {
                    s1p[(size_t)(t0 + s) * HH] = s1v;
                    m1p[(size_t)(t0 + s) * HH] = mem1;
                }

                float cx = s1v * w2x;
                float cy = s1v * w2y;
                wave_sum2(cx, cy);
                if (lane == 63)
                    partv[sc & 1][s][wid] = make_float2(cx, cy);
            }
        } else if (is_prod) {
            // ---- producer: compute next sub-chunk's dots (x via s_load) ----
            if (sc + 1 < NSC) produce(sc + 1);
        } else {
            // ---- wave 8: layer-2 for the previous sub-chunk ----
            if (sc > 0) l2_chunk(sc - 1);
        }

        block_sync_lds();
    }

    // epilogue: layer-2 for the final sub-chunk (wave 8)
    if (wid == 8) {
        l2_chunk(NSC - 1);
        if (tid == 512) {
            outp[b * OO + 0] = (float)accx / 1000.0f;
            outp[b * OO + 1] = (float)accy / 1000.0f;
        }
    }
}

extern "C" void kernel_launch(void* const* d_in, const int* in_sizes, int n_in,
                              void* d_out, int out_size, void* d_ws, size_t ws_size,
                              hipStream_t stream) {
    const float* x  = (const float*)d_in[0];   // [256,1000,32]
    const float* w1 = (const float*)d_in[1];   // [32,200]
    const float* w2 = (const float*)d_in[2];   // [200,2]
    float* out = (float*)d_out;

    dim3 grid(TB), block(576);
    hipLaunchKernelGGL(snn_fwd, grid, block, 0, stream, x, w1, w2, out);
}

// Round 12
// 214.011 us; speedup vs baseline: 2.2558x; 2.2558x over previous
//
#include <hip/hip_runtime.h>

// TwoLayerSNN forward: B=256, T=1000, D=32, H=200, O=2
// Round 12 = round 10 (passing, 197us; r11's global-x experiment reverted)
// with ONE consumer-side change: the per-step sequential DPP tree is split
// out of the recurrence loop into 16 INTERLEAVED chains (phase 2), so the
// ~100cy dependent-latency of each tree is overlapped across chains instead
// of serializing the sub-chunk. Each chain's op order is unchanged ->
// bit-identical partials. s1/m1 (recurrence + stores) complete in phase 1
// before any DPP op issues. Producers / wave-8 layer-2 / xls+dotb staging
// are r10 text verbatim.

constexpr int TB = 256;
constexpr int TT = 1000;
constexpr int DD = 32;
constexpr int HH = 200;
constexpr int OO = 2;
constexpr int CH = 64;                    // timesteps per x staging chunk (8 KB)
constexpr int NCH = (TT + CH - 1) / CH;   // 16
constexpr int SC = 8;                     // timesteps per barrier interval
constexpr int NSC = TT / SC;              // 125

typedef float v2f __attribute__((ext_vector_type(2)));

__device__ __forceinline__ v2f pk_fma(v2f a, v2f b, v2f c) {
#if __has_builtin(__builtin_elementwise_fma)
    return __builtin_elementwise_fma(a, b, c);
#else
    v2f r; r.x = fmaf(a.x, b.x, c.x); r.y = fmaf(a.y, b.y, c.y); return r;
#endif
}

template <int CTRL>
__device__ __forceinline__ float dpp_add(float v) {
    int t = __builtin_amdgcn_update_dpp(0, __float_as_int(v), CTRL, 0xf, 0xf, true);
    return v + __int_as_float(t);
}

__device__ __forceinline__ void block_sync_lds() {
    // Order LDS only (validated r8-r10): drain lgkm, raw barrier.
    asm volatile("s_waitcnt lgkmcnt(0)" ::: "memory");
    __builtin_amdgcn_s_barrier();
    asm volatile("" ::: "memory");
}

__global__ __launch_bounds__(576, 1)
void snn_fwd(const float* __restrict__ x,
             const float* __restrict__ w1,
             const float* __restrict__ w2,
             float* __restrict__ out)
{
    const int b    = blockIdx.x;
    const int tid  = threadIdx.x;
    const int lane = tid & 63;
    const int wid  = tid >> 6;
    const bool is_cons = (wid < 4);             // waves 0-3: consumers
    const bool is_prod = (wid >= 4 && wid < 8); // waves 4-7: producers
    const int ptid = tid - 256;                 // producer-local 0..255
    const bool act = is_cons && (tid < HH);

    float* __restrict__ outp = out;                        // [TB][OO]
    float* __restrict__ s1o  = out + (size_t)TB * OO;      // [TB][TT][HH]
    float* __restrict__ m1o  = s1o + (size_t)TB * TT * HH; // [TB][TT][HH]
    float* __restrict__ s2o  = m1o + (size_t)TB * TT * HH; // [TB][TT][OO]
    float* __restrict__ m2o  = s2o + (size_t)TB * TT * OO; // [TB][TT][OO]

    const float A_SYN1 = (float)0.8187307530779818;
    const float IN_SC1 = (float)((1.0 - 0.8187307530779818) * 5.0);
    const float A_MEM1 = (float)0.9048374180359595;
    const float B_MEM1 = (float)(1.0 - 0.9048374180359595);
    const float TH1    = 0.5f;
    const float A_SYN2 = (float)0.9048374180359595;
    const float IN_SC2 = (float)((1.0 - 0.9048374180359595) * 10.0);
    const float A_MEM2 = (float)0.9512294245007140;
    const float B_MEM2 = (float)(1.0 - 0.9512294245007140);
    const float TH2    = 1.0f;

    __shared__ float4 xls[2][CH * DD / 4];           // 2 x 8 KB
    __shared__ float  dotb[2][SC][HH];               // dot dbuf, 6.4 KB ea
    __shared__ __align__(16) float2 partv[2][SC][4]; // parity x step x wave

    const float* __restrict__ xb = x + (size_t)b * TT * DD;

    // producer: 50 hidden units per wave; w1 column as 16 float2 pairs
    const int ph   = (wid - 4) * 50 + lane;          // producer h
    const bool pact = is_prod && (lane < 50);
    v2f w1e[DD / 4], w1o[DD / 4];
#pragma unroll
    for (int i = 0; i < DD / 4; ++i) {
        w1e[i] = pact ? v2f{w1[(4 * i) * HH + ph],     w1[(4 * i + 1) * HH + ph]} : v2f{0.f, 0.f};
        w1o[i] = pact ? v2f{w1[(4 * i + 2) * HH + ph], w1[(4 * i + 3) * HH + ph]} : v2f{0.f, 0.f};
    }
    // consumer: w2 row
    const float w2x = act ? w2[tid * OO + 0] : 0.0f;
    const float w2y = act ? w2[tid * OO + 1] : 0.0f;

    // stage chunk 0 (8 KB) using consumer threads (one-time)
    if (is_cons) {
        const float4* g = (const float4*)xb;
        xls[0][2 * tid]     = g[2 * tid];
        xls[0][2 * tid + 1] = g[2 * tid + 1];
    }
    block_sync_lds();

    // produce(j): dots for sub-chunk j into dotb[j&1].
    // Bit-identical to r9/r10: pk lanes carry (a0,a1) and (a2,a3) exactly.
    auto produce = [&](int j) {
        const int tj = j * SC;
        const float4* xq = &xls[(tj >> 6) & 1][(tj & 63) * (DD / 4)];
#pragma unroll
        for (int s = 0; s < SC; ++s) {
            const float4 X0 = xq[s * 8 + 0], X1 = xq[s * 8 + 1];
            const float4 X2 = xq[s * 8 + 2], X3 = xq[s * 8 + 3];
            const float4 X4 = xq[s * 8 + 4], X5 = xq[s * 8 + 5];
            const float4 X6 = xq[s * 8 + 6], X7 = xq[s * 8 + 7];
            v2f A01 = {0.f, 0.f}, A23 = {0.f, 0.f};
            A01 = pk_fma(v2f{X0.x, X0.y}, w1e[0], A01);
            A23 = pk_fma(v2f{X0.z, X0.w}, w1o[0], A23);
            A01 = pk_fma(v2f{X1.x, X1.y}, w1e[1], A01);
            A23 = pk_fma(v2f{X1.z, X1.w}, w1o[1], A23);
            A01 = pk_fma(v2f{X2.x, X2.y}, w1e[2], A01);
            A23 = pk_fma(v2f{X2.z, X2.w}, w1o[2], A23);
            A01 = pk_fma(v2f{X3.x, X3.y}, w1e[3], A01);
            A23 = pk_fma(v2f{X3.z, X3.w}, w1o[3], A23);
            A01 = pk_fma(v2f{X4.x, X4.y}, w1e[4], A01);
            A23 = pk_fma(v2f{X4.z, X4.w}, w1o[4], A23);
            A01 = pk_fma(v2f{X5.x, X5.y}, w1e[5], A01);
            A23 = pk_fma(v2f{X5.z, X5.w}, w1o[5], A23);
            A01 = pk_fma(v2f{X6.x, X6.y}, w1e[6], A01);
            A23 = pk_fma(v2f{X6.z, X6.w}, w1o[6], A23);
            A01 = pk_fma(v2f{X7.x, X7.y}, w1e[7], A01);
            A23 = pk_fma(v2f{X7.z, X7.w}, w1o[7], A23);
            const float dotv = __fadd_rn(__fadd_rn(A01.x, A01.y),
                                         __fadd_rn(A23.x, A23.y));
            if (pact) dotb[j & 1][s][ph] = dotv;
        }
    };

    // prologue: fill dotb[0] for sub-chunk 0
    if (is_prod) produce(0);
    block_sync_lds();

    float syn1 = 0.0f, mem1 = 0.0f;
    float syn2x = 0.0f, syn2y = 0.0f, mem2x = 0.0f, mem2y = 0.0f;
    double accx = 0.0, accy = 0.0;

    // PERSISTENT producer staging state (must outlive the loading iteration)
    float4 pr0 = make_float4(0.f, 0.f, 0.f, 0.f);
    float4 pr1 = make_float4(0.f, 0.f, 0.f, 0.f);
    int nfl4 = 0;

    float* __restrict__ s1p = s1o + (size_t)b * TT * HH + tid;
    float* __restrict__ m1p = m1o + (size_t)b * TT * HH + tid;
    float2* __restrict__ s2p = (float2*)(s2o + (size_t)b * TT * OO);
    float2* __restrict__ m2p = (float2*)(m2o + (size_t)b * TT * OO);

    // layer-2 for sub-chunk j (wave 8 only; burst-reads partv[j&1] from LDS)
    auto l2_chunk = [&](int j) {
        float4 P[16];
        const float4* pvall = (const float4*)&partv[j & 1][0][0];
#pragma unroll
        for (int i = 0; i < 16; ++i) P[i] = pvall[i];
#pragma unroll
        for (int s = 0; s < SC; ++s) {
            const float4 q0 = P[2 * s];
            const float4 q1 = P[2 * s + 1];
            const float dx = __fadd_rn(__fadd_rn(q0.x, q0.z), __fadd_rn(q1.x, q1.z));
            const float dy = __fadd_rn(__fadd_rn(q0.y, q0.w), __fadd_rn(q1.y, q1.w));
            syn2x = __fadd_rn(__fmul_rn(A_SYN2, syn2x), __fmul_rn(IN_SC2, dx));
            syn2y = __fadd_rn(__fmul_rn(A_SYN2, syn2y), __fmul_rn(IN_SC2, dy));
            mem2x = __fadd_rn(__fmul_rn(A_MEM2, mem2x), __fmul_rn(B_MEM2, syn2x));
            mem2y = __fadd_rn(__fmul_rn(A_MEM2, mem2y), __fmul_rn(B_MEM2, syn2y));
            const float s2x = (mem2x - TH2 > 0.0f) ? 1.0f : 0.0f;
            const float s2y = (mem2y - TH2 > 0.0f) ? 1.0f : 0.0f;
            mem2x = __fsub_rn(mem2x, __fmul_rn(s2x, TH2));
            mem2y = __fsub_rn(mem2y, __fmul_rn(s2y, TH2));
            const int t = j * SC + s;
            if (tid == 512) {
                s2p[t] = make_float2(s2x, s2y);
                m2p[t] = make_float2(mem2x, mem2y);
            }
            if (t > 0) { accx += (double)mem2x; accy += (double)mem2y; }
        }
    };

    for (int sc = 0; sc < NSC; ++sc) {
        const int t0   = sc * SC;
        const int c    = t0 >> 6;
        const int cpos = t0 & 63;

        if (is_cons) {
            // ---- consumer phase 0: this sub-chunk's dots from LDS ----
            float D[SC];
#pragma unroll
            for (int s = 0; s < SC; ++s) D[s] = dotb[sc & 1][s][tid];

            // ---- phase 1: recurrence + stores (s1/m1 fully done here) ----
            float s1vv[SC];
#pragma unroll
            for (int s = 0; s < SC; ++s) {
                const float dot = D[s];
                syn1 = __fadd_rn(__fmul_rn(A_SYN1, syn1), __fmul_rn(IN_SC1, dot));
                mem1 = __fadd_rn(__fmul_rn(A_MEM1, mem1), __fmul_rn(B_MEM1, syn1));
                const float s1v = (mem1 - TH1 > 0.0f) ? 1.0f : 0.0f;
                mem1 = __fsub_rn(mem1, __fmul_rn(s1v, TH1));
                if (act) {
                    s1p[(size_t)(t0 + s) * HH] = s1v;
                    m1p[(size_t)(t0 + s) * HH] = mem1;
                }
                s1vv[s] = s1v;
            }

            // ---- phase 2: 16 interleaved DPP chains (per-chain order
            //      identical to wave_sum2: shr1,shr2,shr4,shr8,bc15,bc31) ----
            float cx[SC], cy[SC];
#pragma unroll
            for (int s = 0; s < SC; ++s) { cx[s] = s1vv[s] * w2x; cy[s] = s1vv[s] * w2y; }
#define RED_PASS(CTRL)                                                   \
            _Pragma("unroll")                                            \
            for (int s = 0; s < SC; ++s) {                               \
                cx[s] = dpp_add<CTRL>(cx[s]);                            \
                cy[s] = dpp_add<CTRL>(cy[s]);                            \
            }
            RED_PASS(0x111)  // row_shr:1
            RED_PASS(0x112)  // row_shr:2
            RED_PASS(0x114)  // row_shr:4
            RED_PASS(0x118)  // row_shr:8
            RED_PASS(0x142)  // row_bcast:15
            RED_PASS(0x143)  // row_bcast:31
#undef RED_PASS

            if (lane == 63) {
#pragma unroll
                for (int s = 0; s < SC; ++s)
                    partv[sc & 1][s][wid] = make_float2(cx[s], cy[s]);
            }
        } else if (is_prod) {
            // ---- producer: stage x chunks; compute next sub-chunk's dots ----
            if (cpos == 0 && c + 1 < NCH) {
                const int nst = (CH < TT - (c + 1) * CH) ? CH : (TT - (c + 1) * CH);
                nfl4 = nst * DD / 4;
                const float4* g = (const float4*)(xb + (size_t)(c + 1) * CH * DD);
                if (2 * ptid     < nfl4) pr0 = g[2 * ptid];
                if (2 * ptid + 1 < nfl4) pr1 = g[2 * ptid + 1];
            }

            if (sc + 1 < NSC) produce(sc + 1);

            // commit chunk c+1 before producers first read it (at cpos 56)
            if (cpos == 48 && c + 1 < NCH) {
                if (2 * ptid     < nfl4) xls[(c + 1) & 1][2 * ptid]     = pr0;
                if (2 * ptid + 1 < nfl4) xls[(c + 1) & 1][2 * ptid + 1] = pr1;
            }
        } else {
            // ---- wave 8: layer-2 for the previous sub-chunk ----
            if (sc > 0) l2_chunk(sc - 1);
        }

        block_sync_lds();
    }

    // epilogue: layer-2 for the final sub-chunk (wave 8)
    if (wid == 8) {
        l2_chunk(NSC - 1);
        if (tid == 512) {
            outp[b * OO + 0] = (float)accx / 1000.0f;
            outp[b * OO + 1] = (float)accy / 1000.0f;
        }
    }
}

extern "C" void kernel_launch(void* const* d_in, const int* in_sizes, int n_in,
                              void* d_out, int out_size, void* d_ws, size_t ws_size,
                              hipStream_t stream) {
    const float* x  = (const float*)d_in[0];   // [256,1000,32]
    const float* w1 = (const float*)d_in[1];   // [32,200]
    const float* w2 = (const float*)d_in[2];   // [200,2]
    float* out = (float*)d_out;

    dim3 grid(TB), block(576);
    hipLaunchKernelGGL(snn_fwd, grid, block, 0, stream, x, w1, w2, out);
}

// Round 13
// 186.855 us; speedup vs baseline: 2.5836x; 1.1453x over previous
//
#include <hip/hip_runtime.h>

// TwoLayerSNN forward: B=256, T=1000, D=32, H=200, O=2
// Round 13 = round 10 (passing, 197us; r12's phase-split reverted) with the
// consumer DPP tree truncated to 4 levels (row sums @ lanes 15/31/47/63,
// -8 ops/step on the longest wave). The 16 row-partials/step go to
// partv[2][SC][16]; wave 8 merges them LANE-PARALLEL (64 lanes = 4 steps x
// 16 partials, one ds_read_b64 + 4-level DPP per 4 steps + readlane) before
// its serial layer-2 chain. Producers / staging / recurrence text = r10.

constexpr int TB = 256;
constexpr int TT = 1000;
constexpr int DD = 32;
constexpr int HH = 200;
constexpr int OO = 2;
constexpr int CH = 64;                    // timesteps per x staging chunk (8 KB)
constexpr int NCH = (TT + CH - 1) / CH;   // 16
constexpr int SC = 8;                     // timesteps per barrier interval
constexpr int NSC = TT / SC;              // 125

typedef float v2f __attribute__((ext_vector_type(2)));

__device__ __forceinline__ v2f pk_fma(v2f a, v2f b, v2f c) {
#if __has_builtin(__builtin_elementwise_fma)
    return __builtin_elementwise_fma(a, b, c);
#else
    v2f r; r.x = fmaf(a.x, b.x, c.x); r.y = fmaf(a.y, b.y, c.y); return r;
#endif
}

template <int CTRL>
__device__ __forceinline__ float dpp_add(float v) {
    int t = __builtin_amdgcn_update_dpp(0, __float_as_int(v), CTRL, 0xf, 0xf, true);
    return v + __int_as_float(t);
}

__device__ __forceinline__ float read_lane_f(float v, int l) {
    return __int_as_float(__builtin_amdgcn_readlane(__float_as_int(v), l));
}

__device__ __forceinline__ void block_sync_lds() {
    // Order LDS only (validated r8-r10): drain lgkm, raw barrier.
    asm volatile("s_waitcnt lgkmcnt(0)" ::: "memory");
    __builtin_amdgcn_s_barrier();
    asm volatile("" ::: "memory");
}

__global__ __launch_bounds__(576, 1)
void snn_fwd(const float* __restrict__ x,
             const float* __restrict__ w1,
             const float* __restrict__ w2,
             float* __restrict__ out)
{
    const int b    = blockIdx.x;
    const int tid  = threadIdx.x;
    const int lane = tid & 63;
    const int wid  = tid >> 6;
    const bool is_cons = (wid < 4);             // waves 0-3: consumers
    const bool is_prod = (wid >= 4 && wid < 8); // waves 4-7: producers
    const int ptid = tid - 256;                 // producer-local 0..255
    const bool act = is_cons && (tid < HH);

    float* __restrict__ outp = out;                        // [TB][OO]
    float* __restrict__ s1o  = out + (size_t)TB * OO;      // [TB][TT][HH]
    float* __restrict__ m1o  = s1o + (size_t)TB * TT * HH; // [TB][TT][HH]
    float* __restrict__ s2o  = m1o + (size_t)TB * TT * HH; // [TB][TT][OO]
    float* __restrict__ m2o  = s2o + (size_t)TB * TT * OO; // [TB][TT][OO]

    const float A_SYN1 = (float)0.8187307530779818;
    const float IN_SC1 = (float)((1.0 - 0.8187307530779818) * 5.0);
    const float A_MEM1 = (float)0.9048374180359595;
    const float B_MEM1 = (float)(1.0 - 0.9048374180359595);
    const float TH1    = 0.5f;
    const float A_SYN2 = (float)0.9048374180359595;
    const float IN_SC2 = (float)((1.0 - 0.9048374180359595) * 10.0);
    const float A_MEM2 = (float)0.9512294245007140;
    const float B_MEM2 = (float)(1.0 - 0.9512294245007140);
    const float TH2    = 1.0f;

    __shared__ float4 xls[2][CH * DD / 4];           // 2 x 8 KB
    __shared__ float  dotb[2][SC][HH];               // dot dbuf, 6.4 KB ea
    __shared__ __align__(16) float2 partv[2][SC][16]; // parity x step x partial

    const float* __restrict__ xb = x + (size_t)b * TT * DD;

    // producer: 50 hidden units per wave; w1 column as 16 float2 pairs
    const int ph   = (wid - 4) * 50 + lane;          // producer h
    const bool pact = is_prod && (lane < 50);
    v2f w1e[DD / 4], w1o[DD / 4];
#pragma unroll
    for (int i = 0; i < DD / 4; ++i) {
        w1e[i] = pact ? v2f{w1[(4 * i) * HH + ph],     w1[(4 * i + 1) * HH + ph]} : v2f{0.f, 0.f};
        w1o[i] = pact ? v2f{w1[(4 * i + 2) * HH + ph], w1[(4 * i + 3) * HH + ph]} : v2f{0.f, 0.f};
    }
    // consumer: w2 row
    const float w2x = act ? w2[tid * OO + 0] : 0.0f;
    const float w2y = act ? w2[tid * OO + 1] : 0.0f;

    // stage chunk 0 (8 KB) using consumer threads (one-time)
    if (is_cons) {
        const float4* g = (const float4*)xb;
        xls[0][2 * tid]     = g[2 * tid];
        xls[0][2 * tid + 1] = g[2 * tid + 1];
    }
    block_sync_lds();

    // produce(j): dots for sub-chunk j into dotb[j&1]. (r10 text, verified)
    auto produce = [&](int j) {
        const int tj = j * SC;
        const float4* xq = &xls[(tj >> 6) & 1][(tj & 63) * (DD / 4)];
#pragma unroll
        for (int s = 0; s < SC; ++s) {
            const float4 X0 = xq[s * 8 + 0], X1 = xq[s * 8 + 1];
            const float4 X2 = xq[s * 8 + 2], X3 = xq[s * 8 + 3];
            const float4 X4 = xq[s * 8 + 4], X5 = xq[s * 8 + 5];
            const float4 X6 = xq[s * 8 + 6], X7 = xq[s * 8 + 7];
            v2f A01 = {0.f, 0.f}, A23 = {0.f, 0.f};
            A01 = pk_fma(v2f{X0.x, X0.y}, w1e[0], A01);
            A23 = pk_fma(v2f{X0.z, X0.w}, w1o[0], A23);
            A01 = pk_fma(v2f{X1.x, X1.y}, w1e[1], A01);
            A23 = pk_fma(v2f{X1.z, X1.w}, w1o[1], A23);
            A01 = pk_fma(v2f{X2.x, X2.y}, w1e[2], A01);
            A23 = pk_fma(v2f{X2.z, X2.w}, w1o[2], A23);
            A01 = pk_fma(v2f{X3.x, X3.y}, w1e[3], A01);
            A23 = pk_fma(v2f{X3.z, X3.w}, w1o[3], A23);
            A01 = pk_fma(v2f{X4.x, X4.y}, w1e[4], A01);
            A23 = pk_fma(v2f{X4.z, X4.w}, w1o[4], A23);
            A01 = pk_fma(v2f{X5.x, X5.y}, w1e[5], A01);
            A23 = pk_fma(v2f{X5.z, X5.w}, w1o[5], A23);
            A01 = pk_fma(v2f{X6.x, X6.y}, w1e[6], A01);
            A23 = pk_fma(v2f{X6.z, X6.w}, w1o[6], A23);
            A01 = pk_fma(v2f{X7.x, X7.y}, w1e[7], A01);
            A23 = pk_fma(v2f{X7.z, X7.w}, w1o[7], A23);
            const float dotv = __fadd_rn(__fadd_rn(A01.x, A01.y),
                                         __fadd_rn(A23.x, A23.y));
            if (pact) dotb[j & 1][s][ph] = dotv;
        }
    };

    // prologue: fill dotb[0] for sub-chunk 0
    if (is_prod) produce(0);
    block_sync_lds();

    float syn1 = 0.0f, mem1 = 0.0f;
    float syn2x = 0.0f, syn2y = 0.0f, mem2x = 0.0f, mem2y = 0.0f;
    double accx = 0.0, accy = 0.0;

    // PERSISTENT producer staging state (must outlive the loading iteration)
    float4 pr0 = make_float4(0.f, 0.f, 0.f, 0.f);
    float4 pr1 = make_float4(0.f, 0.f, 0.f, 0.f);
    int nfl4 = 0;

    float* __restrict__ s1p = s1o + (size_t)b * TT * HH + tid;
    float* __restrict__ m1p = m1o + (size_t)b * TT * HH + tid;
    float2* __restrict__ s2p = (float2*)(s2o + (size_t)b * TT * OO);
    float2* __restrict__ m2p = (float2*)(m2o + (size_t)b * TT * OO);

    // layer-2 for sub-chunk j (wave 8 only): lane-parallel merge of the 16
    // row-partials per step (4 steps at a time), then the serial chain.
    auto l2_chunk = [&](int j) {
        const int g = lane >> 4;     // step group within half (0..3)
        const int p = lane & 15;     // partial index
#pragma unroll
        for (int half = 0; half < 2; ++half) {
            const float2 v = partv[j & 1][4 * half + g][p];
            float cxv = v.x, cyv = v.y;
            cxv = dpp_add<0x111>(cxv); cyv = dpp_add<0x111>(cyv);
            cxv = dpp_add<0x112>(cxv); cyv = dpp_add<0x112>(cyv);
            cxv = dpp_add<0x114>(cxv); cyv = dpp_add<0x114>(cyv);
            cxv = dpp_add<0x118>(cxv); cyv = dpp_add<0x118>(cyv);
            // row sums now at lanes 15/31/47/63 for steps 4*half+0..3
#pragma unroll
            for (int gg = 0; gg < 4; ++gg) {
                const float dx = read_lane_f(cxv, 16 * gg + 15);
                const float dy = read_lane_f(cyv, 16 * gg + 15);
                syn2x = __fadd_rn(__fmul_rn(A_SYN2, syn2x), __fmul_rn(IN_SC2, dx));
                syn2y = __fadd_rn(__fmul_rn(A_SYN2, syn2y), __fmul_rn(IN_SC2, dy));
                mem2x = __fadd_rn(__fmul_rn(A_MEM2, mem2x), __fmul_rn(B_MEM2, syn2x));
                mem2y = __fadd_rn(__fmul_rn(A_MEM2, mem2y), __fmul_rn(B_MEM2, syn2y));
                const float s2x = (mem2x - TH2 > 0.0f) ? 1.0f : 0.0f;
                const float s2y = (mem2y - TH2 > 0.0f) ? 1.0f : 0.0f;
                mem2x = __fsub_rn(mem2x, __fmul_rn(s2x, TH2));
                mem2y = __fsub_rn(mem2y, __fmul_rn(s2y, TH2));
                const int t = j * SC + 4 * half + gg;
                if (tid == 512) {
                    s2p[t] = make_float2(s2x, s2y);
                    m2p[t] = make_float2(mem2x, mem2y);
                }
                if (t > 0) { accx += (double)mem2x; accy += (double)mem2y; }
            }
        }
    };

    for (int sc = 0; sc < NSC; ++sc) {
        const int t0   = sc * SC;
        const int c    = t0 >> 6;
        const int cpos = t0 & 63;

        if (is_cons) {
            // ---- consumer: this sub-chunk's dots from LDS ----
            float D[SC];
#pragma unroll
            for (int s = 0; s < SC; ++s) D[s] = dotb[sc & 1][s][tid];

            // ---- 8 steps: recurrence + stores + 4-level DPP (r10 order,
            //      truncated after row_shr:8) ----
#pragma unroll
            for (int s = 0; s < SC; ++s) {
                const float dot = D[s];
                syn1 = __fadd_rn(__fmul_rn(A_SYN1, syn1), __fmul_rn(IN_SC1, dot));
                mem1 = __fadd_rn(__fmul_rn(A_MEM1, mem1), __fmul_rn(B_MEM1, syn1));
                const float s1v = (mem1 - TH1 > 0.0f) ? 1.0f : 0.0f;
                mem1 = __fsub_rn(mem1, __fmul_rn(s1v, TH1));

                if (act) {
                    s1p[(size_t)(t0 + s) * HH] = s1v;
                    m1p[(size_t)(t0 + s) * HH] = mem1;
                }

                float cx = s1v * w2x;
                float cy = s1v * w2y;
                cx = dpp_add<0x111>(cx); cy = dpp_add<0x111>(cy);
                cx = dpp_add<0x112>(cx); cy = dpp_add<0x112>(cy);
                cx = dpp_add<0x114>(cx); cy = dpp_add<0x114>(cy);
                cx = dpp_add<0x118>(cx); cy = dpp_add<0x118>(cy);
                // row sums at lanes 15/31/47/63 -> 4 partials per wave
                if ((lane & 15) == 15)
                    partv[sc & 1][s][wid * 4 + (lane >> 4)] = make_float2(cx, cy);
            }
        } else if (is_prod) {
            // ---- producer: stage x chunks; compute next sub-chunk's dots ----
            if (cpos == 0 && c + 1 < NCH) {
                const int nst = (CH < TT - (c + 1) * CH) ? CH : (TT - (c + 1) * CH);
                nfl4 = nst * DD / 4;
                const float4* g = (const float4*)(xb + (size_t)(c + 1) * CH * DD);
                if (2 * ptid     < nfl4) pr0 = g[2 * ptid];
                if (2 * ptid + 1 < nfl4) pr1 = g[2 * ptid + 1];
            }

            if (sc + 1 < NSC) produce(sc + 1);

            // commit chunk c+1 before producers first read it (at cpos 56)
            if (cpos == 48 && c + 1 < NCH) {
                if (2 * ptid     < nfl4) xls[(c + 1) & 1][2 * ptid]     = pr0;
                if (2 * ptid + 1 < nfl4) xls[(c + 1) & 1][2 * ptid + 1] = pr1;
            }
        } else {
            // ---- wave 8: layer-2 for the previous sub-chunk ----
            if (sc > 0) l2_chunk(sc - 1);
        }

        block_sync_lds();
    }

    // epilogue: layer-2 for the final sub-chunk (wave 8)
    if (wid == 8) {
        l2_chunk(NSC - 1);
        if (tid == 512) {
            outp[b * OO + 0] = (float)accx / 1000.0f;
            outp[b * OO + 1] = (float)accy / 1000.0f;
        }
    }
}

extern "C" void kernel_launch(void* const* d_in, const int* in_sizes, int n_in,
                              void* d_out, int out_size, void* d_ws, size_t ws_size,
                              hipStream_t stream) {
    const float* x  = (const float*)d_in[0];   // [256,1000,32]
    const float* w1 = (const float*)d_in[1];   // [32,200]
    const float* w2 = (const float*)d_in[2];   // [200,2]
    float* out = (float*)d_out;

    dim3 grid(TB), block(576);
    hipLaunchKernelGGL(snn_fwd, grid, block, 0, stream, x, w1, w2, out);
}

// Round 14
// 184.121 us; speedup vs baseline: 2.6220x; 1.0148x over previous
//
#include <hip/hip_runtime.h>

// TwoLayerSNN forward: B=256, T=1000, D=32, H=200, O=2
// Round 14 = round 13 (passing, 187us) with:
//  (1) SC 8->20, CH 64->40: barriers 125 -> 50 per launch. Chunk staging is
//      load-at-top / commit-at-bottom of the SAME iteration (r2-validated
//      pattern; no cross-iteration register lifetime).
//  (2) wave-8 layer-2 chain packed as v2f (v_pk_mul/add_f32) with
//      fp contract(off): per-component mul-then-add roundings identical to
//      the scalar __f*_rn chain -> bit-identical numerics, ~half the ops on
//      the overloaded SIMD0.
// Consumer / producer per-step bodies are r13 text verbatim.

constexpr int TB = 256;
constexpr int TT = 1000;
constexpr int DD = 32;
constexpr int HH = 200;
constexpr int OO = 2;
constexpr int CH = 40;                    // timesteps per x staging chunk (5 KB)
constexpr int NCH = TT / CH;              // 25
constexpr int SC = 20;                    // timesteps per barrier interval
constexpr int NSC = TT / SC;              // 50
constexpr int XF4 = CH * DD / 4;          // 320 float4 per chunk

typedef float v2f __attribute__((ext_vector_type(2)));

__device__ __forceinline__ v2f pk_fma(v2f a, v2f b, v2f c) {
#if __has_builtin(__builtin_elementwise_fma)
    return __builtin_elementwise_fma(a, b, c);
#else
    v2f r; r.x = fmaf(a.x, b.x, c.x); r.y = fmaf(a.y, b.y, c.y); return r;
#endif
}

template <int CTRL>
__device__ __forceinline__ float dpp_add(float v) {
    int t = __builtin_amdgcn_update_dpp(0, __float_as_int(v), CTRL, 0xf, 0xf, true);
    return v + __int_as_float(t);
}

__device__ __forceinline__ float read_lane_f(float v, int l) {
    return __int_as_float(__builtin_amdgcn_readlane(__float_as_int(v), l));
}

__device__ __forceinline__ void block_sync_lds() {
    // Order LDS only (validated r8-r13): drain lgkm, raw barrier.
    asm volatile("s_waitcnt lgkmcnt(0)" ::: "memory");
    __builtin_amdgcn_s_barrier();
    asm volatile("" ::: "memory");
}

__global__ __launch_bounds__(576, 1)
void snn_fwd(const float* __restrict__ x,
             const float* __restrict__ w1,
             const float* __restrict__ w2,
             float* __restrict__ out)
{
    const int b    = blockIdx.x;
    const int tid  = threadIdx.x;
    const int lane = tid & 63;
    const int wid  = tid >> 6;
    const bool is_cons = (wid < 4);             // waves 0-3: consumers
    const bool is_prod = (wid >= 4 && wid < 8); // waves 4-7: producers
    const int ptid = tid - 256;                 // producer-local 0..255
    const bool act = is_cons && (tid < HH);

    float* __restrict__ outp = out;                        // [TB][OO]
    float* __restrict__ s1o  = out + (size_t)TB * OO;      // [TB][TT][HH]
    float* __restrict__ m1o  = s1o + (size_t)TB * TT * HH; // [TB][TT][HH]
    float* __restrict__ s2o  = m1o + (size_t)TB * TT * HH; // [TB][TT][OO]
    float* __restrict__ m2o  = s2o + (size_t)TB * TT * OO; // [TB][TT][OO]

    const float A_SYN1 = (float)0.8187307530779818;
    const float IN_SC1 = (float)((1.0 - 0.8187307530779818) * 5.0);
    const float A_MEM1 = (float)0.9048374180359595;
    const float B_MEM1 = (float)(1.0 - 0.9048374180359595);
    const float TH1    = 0.5f;
    const float A_SYN2 = (float)0.9048374180359595;
    const float IN_SC2 = (float)((1.0 - 0.9048374180359595) * 10.0);
    const float A_MEM2 = (float)0.9512294245007140;
    const float B_MEM2 = (float)(1.0 - 0.9512294245007140);
    const float TH2    = 1.0f;

    __shared__ float4 xls[2][XF4];                    // 2 x 5 KB
    __shared__ float  dotb[2][SC][HH];                // 2 x 16 KB
    __shared__ __align__(16) float2 partv[2][SC][16]; // 2 x 2.5 KB

    const float* __restrict__ xb = x + (size_t)b * TT * DD;

    // producer: 50 hidden units per wave; w1 column as 16 float2 pairs
    const int ph   = (wid - 4) * 50 + lane;          // producer h
    const bool pact = is_prod && (lane < 50);
    v2f w1e[DD / 4], w1o[DD / 4];
#pragma unroll
    for (int i = 0; i < DD / 4; ++i) {
        w1e[i] = pact ? v2f{w1[(4 * i) * HH + ph],     w1[(4 * i + 1) * HH + ph]} : v2f{0.f, 0.f};
        w1o[i] = pact ? v2f{w1[(4 * i + 2) * HH + ph], w1[(4 * i + 3) * HH + ph]} : v2f{0.f, 0.f};
    }
    // consumer: w2 row
    const float w2x = act ? w2[tid * OO + 0] : 0.0f;
    const float w2y = act ? w2[tid * OO + 1] : 0.0f;

    // stage chunk 0 (5 KB, 320 float4) using consumer threads (one-time)
    if (is_cons) {
        const float4* g = (const float4*)xb;
        if (2 * tid     < XF4) xls[0][2 * tid]     = g[2 * tid];
        if (2 * tid + 1 < XF4) xls[0][2 * tid + 1] = g[2 * tid + 1];
    }
    block_sync_lds();

    // produce(j): dots for sub-chunk j into dotb[j&1]. (r10/r13 text)
    auto produce = [&](int j) {
        const float4* xq = &xls[(j >> 1) & 1][(j & 1) * SC * (DD / 4)];
#pragma unroll
        for (int s = 0; s < SC; ++s) {
            const float4 X0 = xq[s * 8 + 0], X1 = xq[s * 8 + 1];
            const float4 X2 = xq[s * 8 + 2], X3 = xq[s * 8 + 3];
            const float4 X4 = xq[s * 8 + 4], X5 = xq[s * 8 + 5];
            const float4 X6 = xq[s * 8 + 6], X7 = xq[s * 8 + 7];
            v2f A01 = {0.f, 0.f}, A23 = {0.f, 0.f};
            A01 = pk_fma(v2f{X0.x, X0.y}, w1e[0], A01);
            A23 = pk_fma(v2f{X0.z, X0.w}, w1o[0], A23);
            A01 = pk_fma(v2f{X1.x, X1.y}, w1e[1], A01);
            A23 = pk_fma(v2f{X1.z, X1.w}, w1o[1], A23);
            A01 = pk_fma(v2f{X2.x, X2.y}, w1e[2], A01);
            A23 = pk_fma(v2f{X2.z, X2.w}, w1o[2], A23);
            A01 = pk_fma(v2f{X3.x, X3.y}, w1e[3], A01);
            A23 = pk_fma(v2f{X3.z, X3.w}, w1o[3], A23);
            A01 = pk_fma(v2f{X4.x, X4.y}, w1e[4], A01);
            A23 = pk_fma(v2f{X4.z, X4.w}, w1o[4], A23);
            A01 = pk_fma(v2f{X5.x, X5.y}, w1e[5], A01);
            A23 = pk_fma(v2f{X5.z, X5.w}, w1o[5], A23);
            A01 = pk_fma(v2f{X6.x, X6.y}, w1e[6], A01);
            A23 = pk_fma(v2f{X6.z, X6.w}, w1o[6], A23);
            A01 = pk_fma(v2f{X7.x, X7.y}, w1e[7], A01);
            A23 = pk_fma(v2f{X7.z, X7.w}, w1o[7], A23);
            const float dotv = __fadd_rn(__fadd_rn(A01.x, A01.y),
                                         __fadd_rn(A23.x, A23.y));
            if (pact) dotb[j & 1][s][ph] = dotv;
        }
    };

    // prologue: fill dotb[0] for sub-chunk 0
    if (is_prod) produce(0);
    block_sync_lds();

    float syn1 = 0.0f, mem1 = 0.0f;
    double accx = 0.0, accy = 0.0;
    v2f syn2 = {0.f, 0.f}, mem2 = {0.f, 0.f};
    const v2f A2v  = {A_SYN2, A_SYN2};
    const v2f SC2v = {IN_SC2, IN_SC2};
    const v2f AM2v = {A_MEM2, A_MEM2};
    const v2f BM2v = {B_MEM2, B_MEM2};
    const v2f TH2v = {TH2, TH2};

    float* __restrict__ s1p = s1o + (size_t)b * TT * HH + tid;
    float* __restrict__ m1p = m1o + (size_t)b * TT * HH + tid;
    float2* __restrict__ s2p = (float2*)(s2o + (size_t)b * TT * OO);
    float2* __restrict__ m2p = (float2*)(m2o + (size_t)b * TT * OO);

    // layer-2 for sub-chunk j (wave 8 only): lane-parallel merge of the 16
    // row-partials (4 steps per pass, 5 passes), then the pk-packed serial
    // chain. Per-component roundings identical to the scalar __f*_rn chain.
    auto l2_chunk = [&](int j) {
#pragma clang fp contract(off)
        const int g = lane >> 4;     // step within pass (0..3)
        const int p = lane & 15;     // partial index
#pragma unroll
        for (int half = 0; half < SC / 4; ++half) {
            const float2 v = partv[j & 1][4 * half + g][p];
            float cxv = v.x, cyv = v.y;
            cxv = dpp_add<0x111>(cxv); cyv = dpp_add<0x111>(cyv);
            cxv = dpp_add<0x112>(cxv); cyv = dpp_add<0x112>(cyv);
            cxv = dpp_add<0x114>(cxv); cyv = dpp_add<0x114>(cyv);
            cxv = dpp_add<0x118>(cxv); cyv = dpp_add<0x118>(cyv);
            // merged sums at lanes 15/31/47/63 for steps 4*half+0..3
#pragma unroll
            for (int gg = 0; gg < 4; ++gg) {
                const v2f d = {read_lane_f(cxv, 16 * gg + 15),
                               read_lane_f(cyv, 16 * gg + 15)};
                syn2 = (A2v * syn2) + (SC2v * d);     // pk_mul,pk_mul,pk_add
                mem2 = (AM2v * mem2) + (BM2v * syn2); // pk_mul,pk_mul,pk_add
                const float s2x = (mem2.x - TH2 > 0.0f) ? 1.0f : 0.0f;
                const float s2y = (mem2.y - TH2 > 0.0f) ? 1.0f : 0.0f;
                const v2f s2v = {s2x, s2y};
                mem2 = mem2 - (s2v * TH2v);           // pk_mul,pk_sub
                const int t = j * SC + 4 * half + gg;
                if (tid == 512) {
                    s2p[t] = make_float2(s2x, s2y);
                    m2p[t] = make_float2(mem2.x, mem2.y);
                }
                if (t > 0) { accx += (double)mem2.x; accy += (double)mem2.y; }
            }
        }
    };

    for (int sc = 0; sc < NSC; ++sc) {
        const int t0   = sc * SC;
        const int c    = t0 / CH;
        const int cpos = t0 % CH;

        if (is_cons) {
            // ---- consumer: this sub-chunk's dots from LDS ----
            float D[SC];
#pragma unroll
            for (int s = 0; s < SC; ++s) D[s] = dotb[sc & 1][s][tid];

            // ---- 20 steps: recurrence + stores + 4-level DPP (r13 text) ----
#pragma unroll
            for (int s = 0; s < SC; ++s) {
                const float dot = D[s];
                syn1 = __fadd_rn(__fmul_rn(A_SYN1, syn1), __fmul_rn(IN_SC1, dot));
                mem1 = __fadd_rn(__fmul_rn(A_MEM1, mem1), __fmul_rn(B_MEM1, syn1));
                const float s1v = (mem1 - TH1 > 0.0f) ? 1.0f : 0.0f;
                mem1 = __fsub_rn(mem1, __fmul_rn(s1v, TH1));

                if (act) {
                    s1p[(size_t)(t0 + s) * HH] = s1v;
                    m1p[(size_t)(t0 + s) * HH] = mem1;
                }

                float cx = s1v * w2x;
                float cy = s1v * w2y;
                cx = dpp_add<0x111>(cx); cy = dpp_add<0x111>(cy);
                cx = dpp_add<0x112>(cx); cy = dpp_add<0x112>(cy);
                cx = dpp_add<0x114>(cx); cy = dpp_add<0x114>(cy);
                cx = dpp_add<0x118>(cx); cy = dpp_add<0x118>(cy);
                // row sums at lanes 15/31/47/63 -> 4 partials per wave
                if ((lane & 15) == 15)
                    partv[sc & 1][s][wid * 4 + (lane >> 4)] = make_float2(cx, cy);
            }
        } else if (is_prod) {
            // ---- producer: stage next chunk (same-iteration load/commit);
            //      compute next sub-chunk's dots ----
            float4 pr0, pr1;
            const bool stage = (cpos == 0 && c + 1 < NCH);
            if (stage) {
                const float4* g = (const float4*)(xb + (size_t)(c + 1) * CH * DD);
                if (2 * ptid     < XF4) pr0 = g[2 * ptid];
                if (2 * ptid + 1 < XF4) pr1 = g[2 * ptid + 1];
            }

            if (sc + 1 < NSC) produce(sc + 1);

            if (stage) {
                if (2 * ptid     < XF4) xls[(c + 1) & 1][2 * ptid]     = pr0;
                if (2 * ptid + 1 < XF4) xls[(c + 1) & 1][2 * ptid + 1] = pr1;
            }
        } else {
            // ---- wave 8: layer-2 for the previous sub-chunk ----
            if (sc > 0) l2_chunk(sc - 1);
        }

        block_sync_lds();
    }

    // epilogue: layer-2 for the final sub-chunk (wave 8)
    if (wid == 8) {
        l2_chunk(NSC - 1);
        if (tid == 512) {
            outp[b * OO + 0] = (float)accx / 1000.0f;
            outp[b * OO + 1] = (float)accy / 1000.0f;
        }
    }
}

extern "C" void kernel_launch(void* const* d_in, const int* in_sizes, int n_in,
                              void* d_out, int out_size, void* d_ws, size_t ws_size,
                              hipStream_t stream) {
    const float* x  = (const float*)d_in[0];   // [256,1000,32]
    const float* w1 = (const float*)d_in[1];   // [32,200]
    const float* w2 = (const float*)d_in[2];   // [200,2]
    float* out = (float*)d_out;

    dim3 grid(TB), block(576);
    hipLaunchKernelGGL(snn_fwd, grid, block, 0, stream, x, w1, w2, out);
}

// Round 15
// 182.102 us; speedup vs baseline: 2.6510x; 1.0111x over previous
//
#include <hip/hip_runtime.h>

// TwoLayerSNN forward: B=256, T=1000, D=32, H=200, O=2
// Round 15 = round 14 (passing, 184us) with ONE change: produce() prefetches
// step s+1's x block (8 ds_read_b128) into registers BEFORE step s's fma
// chain, rotating via unrolled register renames. Overlaps the ~100cy LDS
// read latency (previously exposed per step on the producer wave, the
// slowest barrier-bound chain) with the 16 pk_fma of the current step.
// All arithmetic bit-identical to r14; everything else textually r14.

constexpr int TB = 256;
constexpr int TT = 1000;
constexpr int DD = 32;
constexpr int HH = 200;
constexpr int OO = 2;
constexpr int CH = 40;                    // timesteps per x staging chunk (5 KB)
constexpr int NCH = TT / CH;              // 25
constexpr int SC = 20;                    // timesteps per barrier interval
constexpr int NSC = TT / SC;              // 50
constexpr int XF4 = CH * DD / 4;          // 320 float4 per chunk

typedef float v2f __attribute__((ext_vector_type(2)));

__device__ __forceinline__ v2f pk_fma(v2f a, v2f b, v2f c) {
#if __has_builtin(__builtin_elementwise_fma)
    return __builtin_elementwise_fma(a, b, c);
#else
    v2f r; r.x = fmaf(a.x, b.x, c.x); r.y = fmaf(a.y, b.y, c.y); return r;
#endif
}

template <int CTRL>
__device__ __forceinline__ float dpp_add(float v) {
    int t = __builtin_amdgcn_update_dpp(0, __float_as_int(v), CTRL, 0xf, 0xf, true);
    return v + __int_as_float(t);
}

__device__ __forceinline__ float read_lane_f(float v, int l) {
    return __int_as_float(__builtin_amdgcn_readlane(__float_as_int(v), l));
}

__device__ __forceinline__ void block_sync_lds() {
    // Order LDS only (validated r8-r14): drain lgkm, raw barrier.
    asm volatile("s_waitcnt lgkmcnt(0)" ::: "memory");
    __builtin_amdgcn_s_barrier();
    asm volatile("" ::: "memory");
}

__global__ __launch_bounds__(576, 1)
void snn_fwd(const float* __restrict__ x,
             const float* __restrict__ w1,
             const float* __restrict__ w2,
             float* __restrict__ out)
{
    const int b    = blockIdx.x;
    const int tid  = threadIdx.x;
    const int lane = tid & 63;
    const int wid  = tid >> 6;
    const bool is_cons = (wid < 4);             // waves 0-3: consumers
    const bool is_prod = (wid >= 4 && wid < 8); // waves 4-7: producers
    const int ptid = tid - 256;                 // producer-local 0..255
    const bool act = is_cons && (tid < HH);

    float* __restrict__ outp = out;                        // [TB][OO]
    float* __restrict__ s1o  = out + (size_t)TB * OO;      // [TB][TT][HH]
    float* __restrict__ m1o  = s1o + (size_t)TB * TT * HH; // [TB][TT][HH]
    float* __restrict__ s2o  = m1o + (size_t)TB * TT * HH; // [TB][TT][OO]
    float* __restrict__ m2o  = s2o + (size_t)TB * TT * OO; // [TB][TT][OO]

    const float A_SYN1 = (float)0.8187307530779818;
    const float IN_SC1 = (float)((1.0 - 0.8187307530779818) * 5.0);
    const float A_MEM1 = (float)0.9048374180359595;
    const float B_MEM1 = (float)(1.0 - 0.9048374180359595);
    const float TH1    = 0.5f;
    const float A_SYN2 = (float)0.9048374180359595;
    const float IN_SC2 = (float)((1.0 - 0.9048374180359595) * 10.0);
    const float A_MEM2 = (float)0.9512294245007140;
    const float B_MEM2 = (float)(1.0 - 0.9512294245007140);
    const float TH2    = 1.0f;

    __shared__ float4 xls[2][XF4];                    // 2 x 5 KB
    __shared__ float  dotb[2][SC][HH];                // 2 x 16 KB
    __shared__ __align__(16) float2 partv[2][SC][16]; // 2 x 2.5 KB

    const float* __restrict__ xb = x + (size_t)b * TT * DD;

    // producer: 50 hidden units per wave; w1 column as 16 float2 pairs
    const int ph   = (wid - 4) * 50 + lane;          // producer h
    const bool pact = is_prod && (lane < 50);
    v2f w1e[DD / 4], w1o[DD / 4];
#pragma unroll
    for (int i = 0; i < DD / 4; ++i) {
        w1e[i] = pact ? v2f{w1[(4 * i) * HH + ph],     w1[(4 * i + 1) * HH + ph]} : v2f{0.f, 0.f};
        w1o[i] = pact ? v2f{w1[(4 * i + 2) * HH + ph], w1[(4 * i + 3) * HH + ph]} : v2f{0.f, 0.f};
    }
    // consumer: w2 row
    const float w2x = act ? w2[tid * OO + 0] : 0.0f;
    const float w2y = act ? w2[tid * OO + 1] : 0.0f;

    // stage chunk 0 (5 KB, 320 float4) using consumer threads (one-time)
    if (is_cons) {
        const float4* g = (const float4*)xb;
        if (2 * tid     < XF4) xls[0][2 * tid]     = g[2 * tid];
        if (2 * tid + 1 < XF4) xls[0][2 * tid + 1] = g[2 * tid + 1];
    }
    block_sync_lds();

    // produce(j): dots for sub-chunk j into dotb[j&1]. Same fma chain as
    // r10/r13/r14; NEW: 1-step-ahead register prefetch of the x block.
    auto produce = [&](int j) {
        const float4* xq = &xls[(j >> 1) & 1][(j & 1) * SC * (DD / 4)];
        float4 Xc0 = xq[0], Xc1 = xq[1], Xc2 = xq[2], Xc3 = xq[3];
        float4 Xc4 = xq[4], Xc5 = xq[5], Xc6 = xq[6], Xc7 = xq[7];
#pragma unroll
        for (int s = 0; s < SC; ++s) {
            float4 Xn0, Xn1, Xn2, Xn3, Xn4, Xn5, Xn6, Xn7;
            if (s < SC - 1) {
                const float4* nq = xq + (s + 1) * 8;
                Xn0 = nq[0]; Xn1 = nq[1]; Xn2 = nq[2]; Xn3 = nq[3];
                Xn4 = nq[4]; Xn5 = nq[5]; Xn6 = nq[6]; Xn7 = nq[7];
            }
            v2f A01 = {0.f, 0.f}, A23 = {0.f, 0.f};
            A01 = pk_fma(v2f{Xc0.x, Xc0.y}, w1e[0], A01);
            A23 = pk_fma(v2f{Xc0.z, Xc0.w}, w1o[0], A23);
            A01 = pk_fma(v2f{Xc1.x, Xc1.y}, w1e[1], A01);
            A23 = pk_fma(v2f{Xc1.z, Xc1.w}, w1o[1], A23);
            A01 = pk_fma(v2f{Xc2.x, Xc2.y}, w1e[2], A01);
            A23 = pk_fma(v2f{Xc2.z, Xc2.w}, w1o[2], A23);
            A01 = pk_fma(v2f{Xc3.x, Xc3.y}, w1e[3], A01);
            A23 = pk_fma(v2f{Xc3.z, Xc3.w}, w1o[3], A23);
            A01 = pk_fma(v2f{Xc4.x, Xc4.y}, w1e[4], A01);
            A23 = pk_fma(v2f{Xc4.z, Xc4.w}, w1o[4], A23);
            A01 = pk_fma(v2f{Xc5.x, Xc5.y}, w1e[5], A01);
            A23 = pk_fma(v2f{Xc5.z, Xc5.w}, w1o[5], A23);
            A01 = pk_fma(v2f{Xc6.x, Xc6.y}, w1e[6], A01);
            A23 = pk_fma(v2f{Xc6.z, Xc6.w}, w1o[6], A23);
            A01 = pk_fma(v2f{Xc7.x, Xc7.y}, w1e[7], A01);
            A23 = pk_fma(v2f{Xc7.z, Xc7.w}, w1o[7], A23);
            const float dotv = __fadd_rn(__fadd_rn(A01.x, A01.y),
                                         __fadd_rn(A23.x, A23.y));
            if (pact) dotb[j & 1][s][ph] = dotv;
            if (s < SC - 1) {
                Xc0 = Xn0; Xc1 = Xn1; Xc2 = Xn2; Xc3 = Xn3;
                Xc4 = Xn4; Xc5 = Xn5; Xc6 = Xn6; Xc7 = Xn7;
            }
        }
    };

    // prologue: fill dotb[0] for sub-chunk 0
    if (is_prod) produce(0);
    block_sync_lds();

    float syn1 = 0.0f, mem1 = 0.0f;
    double accx = 0.0, accy = 0.0;
    v2f syn2 = {0.f, 0.f}, mem2 = {0.f, 0.f};
    const v2f A2v  = {A_SYN2, A_SYN2};
    const v2f SC2v = {IN_SC2, IN_SC2};
    const v2f AM2v = {A_MEM2, A_MEM2};
    const v2f BM2v = {B_MEM2, B_MEM2};
    const v2f TH2v = {TH2, TH2};

    float* __restrict__ s1p = s1o + (size_t)b * TT * HH + tid;
    float* __restrict__ m1p = m1o + (size_t)b * TT * HH + tid;
    float2* __restrict__ s2p = (float2*)(s2o + (size_t)b * TT * OO);
    float2* __restrict__ m2p = (float2*)(m2o + (size_t)b * TT * OO);

    // layer-2 for sub-chunk j (wave 8 only): lane-parallel merge of the 16
    // row-partials (4 steps per pass, 5 passes), then the pk-packed serial
    // chain (per-component roundings identical to scalar __f*_rn; r14).
    auto l2_chunk = [&](int j) {
#pragma clang fp contract(off)
        const int g = lane >> 4;     // step within pass (0..3)
        const int p = lane & 15;     // partial index
#pragma unroll
        for (int half = 0; half < SC / 4; ++half) {
            const float2 v = partv[j & 1][4 * half + g][p];
            float cxv = v.x, cyv = v.y;
            cxv = dpp_add<0x111>(cxv); cyv = dpp_add<0x111>(cyv);
            cxv = dpp_add<0x112>(cxv); cyv = dpp_add<0x112>(cyv);
            cxv = dpp_add<0x114>(cxv); cyv = dpp_add<0x114>(cyv);
            cxv = dpp_add<0x118>(cxv); cyv = dpp_add<0x118>(cyv);
            // merged sums at lanes 15/31/47/63 for steps 4*half+0..3
#pragma unroll
            for (int gg = 0; gg < 4; ++gg) {
                const v2f d = {read_lane_f(cxv, 16 * gg + 15),
                               read_lane_f(cyv, 16 * gg + 15)};
                syn2 = (A2v * syn2) + (SC2v * d);
                mem2 = (AM2v * mem2) + (BM2v * syn2);
                const float s2x = (mem2.x - TH2 > 0.0f) ? 1.0f : 0.0f;
                const float s2y = (mem2.y - TH2 > 0.0f) ? 1.0f : 0.0f;
                const v2f s2v = {s2x, s2y};
                mem2 = mem2 - (s2v * TH2v);
                const int t = j * SC + 4 * half + gg;
                if (tid == 512) {
                    s2p[t] = make_float2(s2x, s2y);
                    m2p[t] = make_float2(mem2.x, mem2.y);
                }
                if (t > 0) { accx += (double)mem2.x; accy += (double)mem2.y; }
            }
        }
    };

    for (int sc = 0; sc < NSC; ++sc) {
        const int t0   = sc * SC;
        const int c    = t0 / CH;
        const int cpos = t0 % CH;

        if (is_cons) {
            // ---- consumer: this sub-chunk's dots from LDS ----
            float D[SC];
#pragma unroll
            for (int s = 0; s < SC; ++s) D[s] = dotb[sc & 1][s][tid];

            // ---- 20 steps: recurrence + stores + 4-level DPP (r13/r14) ----
#pragma unroll
            for (int s = 0; s < SC; ++s) {
                const float dot = D[s];
                syn1 = __fadd_rn(__fmul_rn(A_SYN1, syn1), __fmul_rn(IN_SC1, dot));
                mem1 = __fadd_rn(__fmul_rn(A_MEM1, mem1), __fmul_rn(B_MEM1, syn1));
                const float s1v = (mem1 - TH1 > 0.0f) ? 1.0f : 0.0f;
                mem1 = __fsub_rn(mem1, __fmul_rn(s1v, TH1));

                if (act) {
                    s1p[(size_t)(t0 + s) * HH] = s1v;
                    m1p[(size_t)(t0 + s) * HH] = mem1;
                }

                float cx = s1v * w2x;
                float cy = s1v * w2y;
                cx = dpp_add<0x111>(cx); cy = dpp_add<0x111>(cy);
                cx = dpp_add<0x112>(cx); cy = dpp_add<0x112>(cy);
                cx = dpp_add<0x114>(cx); cy = dpp_add<0x114>(cy);
                cx = dpp_add<0x118>(cx); cy = dpp_add<0x118>(cy);
                // row sums at lanes 15/31/47/63 -> 4 partials per wave
                if ((lane & 15) == 15)
                    partv[sc & 1][s][wid * 4 + (lane >> 4)] = make_float2(cx, cy);
            }
        } else if (is_prod) {
            // ---- producer: stage next chunk (same-iteration load/commit);
            //      compute next sub-chunk's dots ----
            float4 pr0, pr1;
            const bool stage = (cpos == 0 && c + 1 < NCH);
            if (stage) {
                const float4* g = (const float4*)(xb + (size_t)(c + 1) * CH * DD);
                if (2 * ptid     < XF4) pr0 = g[2 * ptid];
                if (2 * ptid + 1 < XF4) pr1 = g[2 * ptid + 1];
            }

            if (sc + 1 < NSC) produce(sc + 1);

            if (stage) {
                if (2 * ptid     < XF4) xls[(c + 1) & 1][2 * ptid]     = pr0;
                if (2 * ptid + 1 < XF4) xls[(c + 1) & 1][2 * ptid + 1] = pr1;
            }
        } else {
            // ---- wave 8: layer-2 for the previous sub-chunk ----
            if (sc > 0) l2_chunk(sc - 1);
        }

        block_sync_lds();
    }

    // epilogue: layer-2 for the final sub-chunk (wave 8)
    if (wid == 8) {
        l2_chunk(NSC - 1);
        if (tid == 512) {
            outp[b * OO + 0] = (float)accx / 1000.0f;
            outp[b * OO + 1] = (float)accy / 1000.0f;
        }
    }
}

extern "C" void kernel_launch(void* const* d_in, const int* in_sizes, int n_in,
                              void* d_out, int out_size, void* d_ws, size_t ws_size,
                              hipStream_t stream) {
    const float* x  = (const float*)d_in[0];   // [256,1000,32]
    const float* w1 = (const float*)d_in[1];   // [32,200]
    const float* w2 = (const float*)d_in[2];   // [200,2]
    float* out = (float*)d_out;

    dim3 grid(TB), block(576);
    hipLaunchKernelGGL(snn_fwd, grid, block, 0, stream, x, w1, w2, out);
}